// Round 4
// baseline (1939.074 us; speedup 1.0000x reference)
//
#include <hip/hip_runtime.h>
#include <stdint.h>

#define B_ 4
#define N_ 4096
#define C1_ 58
#define K_ 32
#define EPS_ 1e-5f

typedef __attribute__((ext_vector_type(8))) short bf16x8;
typedef __attribute__((ext_vector_type(4))) float f32x4;

static __device__ __forceinline__ float bf2f(unsigned short u){
  return __uint_as_float(((unsigned int)u) << 16);
}
static __device__ __forceinline__ unsigned short f2bf(float f){
  unsigned int x = __float_as_uint(f);
  x = (x + 0x7FFFu + ((x >> 16) & 1u)) >> 16;
  return (unsigned short)x;
}

// ---------------- ball query (wave-parallel) ----------------
__global__ __launch_bounds__(256) void ball_kernel(const float* __restrict__ xyz,
                                                   int* __restrict__ inds){
  const int wid  = (blockIdx.x * 256 + threadIdx.x) >> 6;
  const int lane = threadIdx.x & 63;
  const int b = wid >> 12;
  const int n = wid & (N_ - 1);
  const float* xb = xyz + (size_t)b * N_ * 3;
  const float qx = xb[n*3+0], qy = xb[n*3+1], qz = xb[n*3+2];
  const float R2 = (float)(0.3 * 0.3);
  int* outp = inds + (size_t)wid * K_;
  int cnt = 0;
  int first = -1;
  for (int j0 = 0; j0 < N_ && cnt < K_; j0 += 64){
    const int j = j0 + lane;
    float dx = xb[j*3+0] - qx;
    float dy = xb[j*3+1] - qy;
    float dz = xb[j*3+2] - qz;
    float s = __fadd_rn(__fadd_rn(__fmul_rn(dx,dx), __fmul_rn(dy,dy)), __fmul_rn(dz,dz));
    bool p = (s <= R2);
    unsigned long long mask = __ballot(p);
    if (p){
      int pos = cnt + __popcll(mask & ((1ull << lane) - 1ull));
      if (pos < K_) outp[pos] = j;
    }
    if (first < 0 && mask) first = j0 + __builtin_ctzll(mask);
    cnt += __popcll(mask);
  }
  if (lane < K_ && lane >= cnt) outp[lane] = first;
}

// ---------------- GEMM-tiled MFMA conv layer ----------------
// Rows are flat m = (b*N + n)*K + k.  Block = 4 waves, ROWS = 64*MPW rows.
// MODE_IN : 0 = gather/concat new_points, 1 = bf16 x + folded GN+relu (sc,sb)
// MODE_OUT: 0 = Y -> LDS -> coalesced bf16 store + group stats
//           2 = group stats + per-point max/min over k (1 point per wave)
template<int COUT, int MODE_IN, int MODE_OUT, int MPW>
__global__ __launch_bounds__(256)
void conv_gemm(const float* __restrict__ feature, const float* __restrict__ xyz,
               const int* __restrict__ inds,
               const unsigned short* __restrict__ xin,
               const float* __restrict__ scin, const float* __restrict__ sbin,
               const float* __restrict__ Wg,
               unsigned short* __restrict__ xout, float* __restrict__ sums,
               float* __restrict__ ymax, float* __restrict__ ymin)
{
  constexpr int ROWS = 64 * MPW;          // rows per block (256 or 128)
  constexpr int NT   = COUT / 16;
  constexpr int NG   = COUT / 32;         // channel groups
  constexpr int YPAD = 72;                // Y-tile row pad (shorts): 144B stride
  constexpr int XYSZ = (MODE_OUT == 0) ? (ROWS * YPAD) : (ROWS * 64);

  __shared__ unsigned short Wl[COUT * 64];     // W bf16, chunk c at c^(ch&7)
  __shared__ unsigned short Xl[XYSZ];          // X tile (then Y tile if MODE_OUT==0)
  __shared__ int sidx[(MODE_IN == 0) ? ROWS : 1];

  const int t = threadIdx.x;
  const int bid = blockIdx.x;
  const size_t row0 = (size_t)bid * ROWS;
  const int b = (int)(row0 >> 17);             // rows per batch = N*K = 2^17
  const int lane = t & 63, w = t >> 6;
  const int col = lane & 15, quad = lane >> 4;

  // ---- stage W: f32 -> bf16 LDS, swizzled ----
  #pragma unroll
  for (int i = 0; i < COUT * 8 / 256; ++i){
    int idx = i * 256 + t;
    int ch = idx >> 3, c = idx & 7;
    const float* wr = Wg + ch * 64 + c * 8;
    bf16x8 v;
    #pragma unroll
    for (int j = 0; j < 8; ++j) v[j] = (short)f2bf(wr[j]);
    *(bf16x8*)&Wl[ch * 64 + ((c ^ (ch & 7)) * 8)] = v;
  }

  // ---- stage X tile (ROWS x 64 bf16), swizzled chunk c at c^(r&7) ----
  if constexpr (MODE_IN == 0){
    for (int i = t; i < ROWS; i += 256) sidx[i] = inds[row0 + i];  // inds flat == row
    __syncthreads();
    const size_t pb = (size_t)b * N_;
    #pragma unroll
    for (int i = 0; i < ROWS / 32; ++i){
      int task = i * 256 + t;
      int r = task >> 3, c = task & 7;
      int n = (int)(((row0 + r) >> 5) & (N_ - 1));
      const float* ctr = xyz + (pb + n) * 3;
      float cx = ctr[0], cy = ctr[1], cz = ctr[2];
      int idx = sidx[r];
      const float* nb = xyz + (pb + idx) * 3;
      const float* frow = feature + (pb + idx) * C1_;
      bf16x8 v;
      #pragma unroll
      for (int j = 0; j < 8; ++j){
        int c0 = c * 8 + j;
        float val;
        if (c0 == 0)      val = cx;
        else if (c0 == 1) val = cy;
        else if (c0 == 2) val = cz;
        else if (c0 < 6){
          float cc = (c0 == 3) ? cx : (c0 == 4) ? cy : cz;
          val = nb[c0 - 3] - cc;
        } else            val = frow[c0 - 6];
        v[j] = (short)f2bf(val);
      }
      *(bf16x8*)&Xl[r * 64 + ((c ^ (r & 7)) * 8)] = v;
    }
  } else {
    const int c8 = t & 7;                       // this thread's fixed 8 channels
    float sc[8], sb[8];
    #pragma unroll
    for (int j = 0; j < 8; ++j){
      sc[j] = scin[b * 64 + c8 * 8 + j];
      sb[j] = sbin[b * 64 + c8 * 8 + j];
    }
    const uint4* src = (const uint4*)xin + row0 * 8;
    #pragma unroll
    for (int i = 0; i < ROWS / 32; ++i){
      int task = i * 256 + t;
      int r = task >> 3;
      uint4 raw = src[task];                    // fully coalesced 16B/thread
      const unsigned short* u = (const unsigned short*)&raw;
      bf16x8 v;
      #pragma unroll
      for (int j = 0; j < 8; ++j){
        float x = bf2f(u[j]);
        float y = fmaf(x, sc[j], sb[j]);
        y = fmaxf(y, 0.f);
        v[j] = (short)f2bf(y);
      }
      *(bf16x8*)&Xl[r * 64 + ((c8 ^ (r & 7)) * 8)] = v;
    }
  }
  __syncthreads();

  // ---- A fragments (registers) ----
  bf16x8 afr[MPW][2];
  #pragma unroll
  for (int mi = 0; mi < MPW; ++mi){
    int r = w * (MPW * 16) + mi * 16 + col;
    #pragma unroll
    for (int kt = 0; kt < 2; ++kt)
      afr[mi][kt] = *(const bf16x8*)&Xl[r * 64 + (((kt * 4 + quad) ^ (r & 7)) * 8)];
  }

  // ---- MFMA ----
  f32x4 acc[MPW][NT];
  #pragma unroll
  for (int mi = 0; mi < MPW; ++mi)
    #pragma unroll
    for (int nt = 0; nt < NT; ++nt) acc[mi][nt] = (f32x4){0.f, 0.f, 0.f, 0.f};

  #pragma unroll
  for (int kt = 0; kt < 2; ++kt){
    #pragma unroll
    for (int nt = 0; nt < NT; ++nt){
      int ch = nt * 16 + col;
      bf16x8 bfr = *(const bf16x8*)&Wl[ch * 64 + (((kt * 4 + quad) ^ (ch & 7)) * 8)];
      #pragma unroll
      for (int mi = 0; mi < MPW; ++mi)
        acc[mi][nt] = __builtin_amdgcn_mfma_f32_16x16x32_bf16(afr[mi][kt], bfr, acc[mi][nt], 0, 0, 0);
    }
  }

  // ---- group stats on raw y ----
  float sg[NG], qg[NG];
  #pragma unroll
  for (int g = 0; g < NG; ++g){ sg[g] = 0.f; qg[g] = 0.f; }
  #pragma unroll
  for (int mi = 0; mi < MPW; ++mi)
    #pragma unroll
    for (int nt = 0; nt < NT; ++nt)
      #pragma unroll
      for (int rg = 0; rg < 4; ++rg){
        float y = acc[mi][nt][rg];
        sg[nt >> 1] += y;
        qg[nt >> 1] = fmaf(y, y, qg[nt >> 1]);
      }

  if constexpr (MODE_OUT == 0){
    // Y -> LDS (pad-72 rows) -> coalesced 128B/thread global store
    __syncthreads();   // all waves done reading Xl as X
    #pragma unroll
    for (int mi = 0; mi < MPW; ++mi)
      #pragma unroll
      for (int nt = 0; nt < NT; ++nt)
        #pragma unroll
        for (int rg = 0; rg < 4; ++rg)
          Xl[(w * MPW * 16 + mi * 16 + quad * 4 + rg) * YPAD + nt * 16 + col] =
              f2bf(acc[mi][nt][rg]);
    __syncthreads();
    uint4* dst = (uint4*)xout + (row0 + t) * 8;
    const uint4* srcy = (const uint4*)&Xl[(size_t)t * YPAD];
    #pragma unroll
    for (int j = 0; j < 8; ++j) dst[j] = srcy[j];
  } else {
    // 1 point per wave (MPW==2): k-reduce max/min fully in-wave
    float cmx[NT], cmn[NT];
    #pragma unroll
    for (int nt = 0; nt < NT; ++nt){
      float mx = acc[0][nt][0], mn = acc[0][nt][0];
      #pragma unroll
      for (int mi = 0; mi < MPW; ++mi)
        #pragma unroll
        for (int rg = 0; rg < 4; ++rg){
          float y = acc[mi][nt][rg];
          mx = fmaxf(mx, y); mn = fminf(mn, y);
        }
      mx = fmaxf(mx, __shfl_xor(mx, 16, 64));
      mx = fmaxf(mx, __shfl_xor(mx, 32, 64));
      mn = fminf(mn, __shfl_xor(mn, 16, 64));
      mn = fminf(mn, __shfl_xor(mn, 32, 64));
      cmx[nt] = mx; cmn[nt] = mn;
    }
    if (quad == 0){
      size_t pt = (row0 >> 5) + w;
      #pragma unroll
      for (int nt = 0; nt < NT; ++nt){
        ymax[pt * 128 + nt * 16 + col] = cmx[nt];
        ymin[pt * 128 + nt * 16 + col] = cmn[nt];
      }
    }
  }

  // ---- stats epilogue ----
  #pragma unroll
  for (int g = 0; g < NG; ++g){
    #pragma unroll
    for (int off = 32; off > 0; off >>= 1){
      sg[g] += __shfl_down(sg[g], off, 64);
      qg[g] += __shfl_down(qg[g], off, 64);
    }
  }
  if (lane == 0){
    #pragma unroll
    for (int g = 0; g < NG; ++g){
      atomicAdd(&sums[(b * 4 + g) * 2 + 0], sg[g]);
      atomicAdd(&sums[(b * 4 + g) * 2 + 1], qg[g]);
    }
  }
}

// ---------------- stats finalize: fold GN affine into per-(b,ch) scale/bias ----
__global__ void finalize_kernel(const float* __restrict__ sums,
                                const float* __restrict__ g, const float* __restrict__ bb,
                                float* __restrict__ sc, float* __restrict__ sb, int nch){
  int t = blockIdx.x * blockDim.x + threadIdx.x;
  if (t >= 4 * nch) return;
  int b = t / nch, c = t % nch;
  int grp = c >> 5;
  const float cnt = 4194304.f;   // 32 ch * K * N
  float s = sums[(b*4+grp)*2+0], s2v = sums[(b*4+grp)*2+1];
  float mean = s / cnt;
  float var = s2v / cnt - mean * mean;
  float rstd = 1.f / sqrtf(var + EPS_);
  float scale = rstd * g[c];
  sc[b*nch + c] = scale;
  sb[b*nch + c] = bb[c] - mean * scale;
}

// ---------------- final: GN2+relu on k-extremum, transpose [b][n][128]->[b][128][n] ----
__global__ __launch_bounds__(256)
void out_kernel(const float* __restrict__ ymax, const float* __restrict__ ymin,
                const float* __restrict__ sc2, const float* __restrict__ sb2,
                float* __restrict__ out){
  __shared__ float tile[64 * 129];
  const int t = threadIdx.x;
  const int b = blockIdx.y;
  const int n0 = blockIdx.x * 64;
  const float4* mx4 = (const float4*)(ymax + ((size_t)b * N_ + n0) * 128);
  const float4* mn4 = (const float4*)(ymin + ((size_t)b * N_ + n0) * 128);
  #pragma unroll
  for (int i = 0; i < 8; ++i){
    int e4 = i * 256 + t;
    int nl = e4 >> 5;
    int ch0 = (e4 & 31) * 4;
    float4 vx = mx4[e4], vn = mn4[e4];
    #pragma unroll
    for (int j = 0; j < 4; ++j){
      float slope = sc2[b*128 + ch0 + j];
      float off   = sb2[b*128 + ch0 + j];
      float y = (slope >= 0.f) ? ((const float*)&vx)[j] : ((const float*)&vn)[j];
      float v = fmaf(y, slope, off);
      tile[nl*129 + ch0 + j] = v > 0.f ? v : 0.f;
    }
  }
  __syncthreads();
  const int ch = t >> 1, h = t & 1;
  float* orow = out + ((size_t)b * 128 + ch) * N_ + n0 + h * 32;
  #pragma unroll
  for (int jj = 0; jj < 8; ++jj){
    float4 v;
    #pragma unroll
    for (int c = 0; c < 4; ++c)
      ((float*)&v)[c] = tile[(h*32 + jj*4 + c)*129 + ch];
    ((float4*)orow)[jj] = v;
  }
}

extern "C" void kernel_launch(void* const* d_in, const int* in_sizes, int n_in,
                              void* d_out, int out_size, void* d_ws, size_t ws_size,
                              hipStream_t stream) {
  const float* feature = (const float*)d_in[0];
  const float* xyz     = (const float*)d_in[1];
  const float* W0 = (const float*)d_in[2];
  const float* g0 = (const float*)d_in[3];
  const float* b0 = (const float*)d_in[4];
  const float* W1 = (const float*)d_in[5];
  const float* g1 = (const float*)d_in[6];
  const float* b1 = (const float*)d_in[7];
  const float* W2 = (const float*)d_in[8];
  const float* g2 = (const float*)d_in[9];
  const float* b2 = (const float*)d_in[10];
  float* out = (float*)d_out;

  char* ws = (char*)d_ws;
  const size_t INDS_BYTES = (size_t)B_ * N_ * K_ * sizeof(int);   // 2 MiB
  const size_t XBYTES     = (size_t)B_ * N_ * K_ * 64 * 2;        // 64 MiB each
  const size_t YBYTES     = (size_t)B_ * N_ * 128 * sizeof(float);// 8 MiB each
  int* inds           = (int*)ws;
  unsigned short* x1  = (unsigned short*)(ws + INDS_BYTES);          // [2,66) MiB
  unsigned short* x0  = (unsigned short*)(ws + INDS_BYTES + XBYTES); // [66,130) MiB
  float* ymax         = (float*)(ws + INDS_BYTES + XBYTES);          // overlays dead x0
  float* ymin         = (float*)(ws + INDS_BYTES + XBYTES + YBYTES);
  float* sums         = (float*)(ws + INDS_BYTES + 2 * XBYTES);      // [3][B][4][2]
  float* sc0 = sums + 96;          // [4][64]
  float* sb0 = sc0 + 256;
  float* sc1 = sb0 + 256;
  float* sb1 = sc1 + 256;
  float* sc2 = sb1 + 256;          // [4][128]
  float* sb2 = sc2 + 512;

  hipMemsetAsync(sums, 0, 96 * sizeof(float), stream);

  ball_kernel<<<B_ * N_ / 4, 256, 0, stream>>>(xyz, inds);

  const int MROWS = B_ * N_ * K_;   // 524288

  // layer 0: gather/concat -> MFMA -> raw bf16 x0 + stats
  conv_gemm<64, 0, 0, 4><<<MROWS / 256, 256, 0, stream>>>(
      feature, xyz, inds, nullptr, nullptr, nullptr,
      W0, x0, sums + 0, nullptr, nullptr);
  finalize_kernel<<<1, 256, 0, stream>>>(sums + 0, g0, b0, sc0, sb0, 64);

  // layer 1: GN0+relu(x0) -> MFMA -> raw bf16 x1 + stats
  conv_gemm<64, 1, 0, 4><<<MROWS / 256, 256, 0, stream>>>(
      nullptr, nullptr, nullptr, x0, sc0, sb0,
      W1, x1, sums + 32, nullptr, nullptr);
  finalize_kernel<<<1, 256, 0, stream>>>(sums + 32, g1, b1, sc1, sb1, 64);

  // layer 2: GN1+relu(x1) -> MFMA -> stats + max/min over k
  conv_gemm<128, 1, 2, 2><<<MROWS / 128, 256, 0, stream>>>(
      nullptr, nullptr, nullptr, x1, sc1, sb1,
      W2, nullptr, sums + 64, ymax, ymin);
  finalize_kernel<<<2, 256, 0, stream>>>(sums + 64, g2, b2, sc2, sb2, 128);

  // final: GN2+relu on extremum + transpose to [b][128][n]
  dim3 ogrid(N_ / 64, B_);
  out_kernel<<<ogrid, 256, 0, stream>>>(ymax, ymin, sc2, sb2, out);
}

// Round 5
// 167.781 us; speedup vs baseline: 11.5571x; 11.5571x over previous
//
#include <hip/hip_runtime.h>
#include <stdint.h>

#define B_ 4
#define N_ 4096
#define C1_ 58
#define K_ 32
#define EPS_ 1e-5f
#define NSLOT 32          // atomic-spread slots (each slot = own cache line)
#define SLOTF 64          // floats per slot (256 B)

typedef __attribute__((ext_vector_type(8))) short bf16x8;
typedef __attribute__((ext_vector_type(4))) float f32x4;

static __device__ __forceinline__ float bf2f(unsigned short u){
  return __uint_as_float(((unsigned int)u) << 16);
}
static __device__ __forceinline__ unsigned short f2bf(float f){
  unsigned int x = __float_as_uint(f);
  x = (x + 0x7FFFu + ((x >> 16) & 1u)) >> 16;
  return (unsigned short)x;
}

// ---------------- ball query (wave-parallel) ----------------
__global__ __launch_bounds__(256) void ball_kernel(const float* __restrict__ xyz,
                                                   int* __restrict__ inds){
  const int wid  = (blockIdx.x * 256 + threadIdx.x) >> 6;
  const int lane = threadIdx.x & 63;
  const int b = wid >> 12;
  const int n = wid & (N_ - 1);
  const float* xb = xyz + (size_t)b * N_ * 3;
  const float qx = xb[n*3+0], qy = xb[n*3+1], qz = xb[n*3+2];
  const float R2 = (float)(0.3 * 0.3);
  int* outp = inds + (size_t)wid * K_;
  int cnt = 0;
  int first = -1;
  for (int j0 = 0; j0 < N_ && cnt < K_; j0 += 64){
    const int j = j0 + lane;
    float dx = xb[j*3+0] - qx;
    float dy = xb[j*3+1] - qy;
    float dz = xb[j*3+2] - qz;
    float s = __fadd_rn(__fadd_rn(__fmul_rn(dx,dx), __fmul_rn(dy,dy)), __fmul_rn(dz,dz));
    bool p = (s <= R2);
    unsigned long long mask = __ballot(p);
    if (p){
      int pos = cnt + __popcll(mask & ((1ull << lane) - 1ull));
      if (pos < K_) outp[pos] = j;
    }
    if (first < 0 && mask) first = j0 + __builtin_ctzll(mask);
    cnt += __popcll(mask);
  }
  if (lane < K_ && lane >= cnt) outp[lane] = first;
}

// ---------------- GEMM-tiled MFMA conv layer ----------------
// Rows are flat m = (b*N + n)*K + k.  Block = 4 waves, ROWS = 64*MPW rows.
// MODE_IN : 0 = gather/concat new_points, 1 = bf16 x + folded GN+relu (sc,sb)
// MODE_OUT: 0 = Y -> LDS -> coalesced bf16 store + group stats
//           2 = group stats + per-point max/min over k (1 point per wave)
// Stats: per-wave shfl reduce -> LDS -> ONE thread-set per block ->
//        atomicAdd into 32 line-separated slots (kills same-line serialization).
template<int COUT, int MODE_IN, int MODE_OUT, int MPW>
__global__ __launch_bounds__(256)
void conv_gemm(const float* __restrict__ feature, const float* __restrict__ xyz,
               const int* __restrict__ inds,
               const unsigned short* __restrict__ xin,
               const float* __restrict__ scin, const float* __restrict__ sbin,
               const float* __restrict__ Wg,
               unsigned short* __restrict__ xout, float* __restrict__ sums,
               float* __restrict__ ymax, float* __restrict__ ymin)
{
  constexpr int ROWS = 64 * MPW;          // rows per block (256 or 128)
  constexpr int NT   = COUT / 16;
  constexpr int NG   = COUT / 32;         // channel groups
  constexpr int YPAD = 72;                // Y-tile row pad (shorts): 144B stride
  constexpr int XYSZ = (MODE_OUT == 0) ? (ROWS * YPAD) : (ROWS * 64);

  __shared__ unsigned short Wl[COUT * 64];     // W bf16, chunk c at c^(ch&7)
  __shared__ unsigned short Xl[XYSZ];          // X tile (then Y tile if MODE_OUT==0)
  __shared__ int sidx[(MODE_IN == 0) ? ROWS : 1];
  __shared__ float spart[4][NG * 2];           // per-wave stat partials

  const int t = threadIdx.x;
  const int bid = blockIdx.x;
  const size_t row0 = (size_t)bid * ROWS;
  const int b = (int)(row0 >> 17);             // rows per batch = N*K = 2^17
  const int lane = t & 63, w = t >> 6;
  const int col = lane & 15, quad = lane >> 4;

  // ---- stage W: f32 -> bf16 LDS, swizzled ----
  #pragma unroll
  for (int i = 0; i < COUT * 8 / 256; ++i){
    int idx = i * 256 + t;
    int ch = idx >> 3, c = idx & 7;
    const float* wr = Wg + ch * 64 + c * 8;
    bf16x8 v;
    #pragma unroll
    for (int j = 0; j < 8; ++j) v[j] = (short)f2bf(wr[j]);
    *(bf16x8*)&Wl[ch * 64 + ((c ^ (ch & 7)) * 8)] = v;
  }

  // ---- stage X tile (ROWS x 64 bf16), swizzled chunk c at c^(r&7) ----
  if constexpr (MODE_IN == 0){
    for (int i = t; i < ROWS; i += 256) sidx[i] = inds[row0 + i];  // inds flat == row
    __syncthreads();
    const size_t pb = (size_t)b * N_;
    #pragma unroll
    for (int i = 0; i < ROWS / 32; ++i){
      int task = i * 256 + t;
      int r = task >> 3, c = task & 7;
      int n = (int)(((row0 + r) >> 5) & (N_ - 1));
      const float* ctr = xyz + (pb + n) * 3;
      float cx = ctr[0], cy = ctr[1], cz = ctr[2];
      int idx = sidx[r];
      const float* nb = xyz + (pb + idx) * 3;
      const float* frow = feature + (pb + idx) * C1_;
      bf16x8 v;
      #pragma unroll
      for (int j = 0; j < 8; ++j){
        int c0 = c * 8 + j;
        float val;
        if (c0 == 0)      val = cx;
        else if (c0 == 1) val = cy;
        else if (c0 == 2) val = cz;
        else if (c0 < 6){
          float cc = (c0 == 3) ? cx : (c0 == 4) ? cy : cz;
          val = nb[c0 - 3] - cc;
        } else            val = frow[c0 - 6];
        v[j] = (short)f2bf(val);
      }
      *(bf16x8*)&Xl[r * 64 + ((c ^ (r & 7)) * 8)] = v;
    }
  } else {
    const int c8 = t & 7;                       // this thread's fixed 8 channels
    float sc[8], sb[8];
    #pragma unroll
    for (int j = 0; j < 8; ++j){
      sc[j] = scin[b * 64 + c8 * 8 + j];
      sb[j] = sbin[b * 64 + c8 * 8 + j];
    }
    const uint4* src = (const uint4*)xin + row0 * 8;
    #pragma unroll
    for (int i = 0; i < ROWS / 32; ++i){
      int task = i * 256 + t;
      int r = task >> 3;
      uint4 raw = src[task];                    // fully coalesced 16B/thread
      const unsigned short* u = (const unsigned short*)&raw;
      bf16x8 v;
      #pragma unroll
      for (int j = 0; j < 8; ++j){
        float x = bf2f(u[j]);
        float y = fmaf(x, sc[j], sb[j]);
        y = fmaxf(y, 0.f);
        v[j] = (short)f2bf(y);
      }
      *(bf16x8*)&Xl[r * 64 + ((c8 ^ (r & 7)) * 8)] = v;
    }
  }
  __syncthreads();

  // ---- A fragments (registers) ----
  bf16x8 afr[MPW][2];
  #pragma unroll
  for (int mi = 0; mi < MPW; ++mi){
    int r = w * (MPW * 16) + mi * 16 + col;
    #pragma unroll
    for (int kt = 0; kt < 2; ++kt)
      afr[mi][kt] = *(const bf16x8*)&Xl[r * 64 + (((kt * 4 + quad) ^ (r & 7)) * 8)];
  }

  // ---- MFMA ----
  f32x4 acc[MPW][NT];
  #pragma unroll
  for (int mi = 0; mi < MPW; ++mi)
    #pragma unroll
    for (int nt = 0; nt < NT; ++nt) acc[mi][nt] = (f32x4){0.f, 0.f, 0.f, 0.f};

  #pragma unroll
  for (int kt = 0; kt < 2; ++kt){
    #pragma unroll
    for (int nt = 0; nt < NT; ++nt){
      int ch = nt * 16 + col;
      bf16x8 bfr = *(const bf16x8*)&Wl[ch * 64 + (((kt * 4 + quad) ^ (ch & 7)) * 8)];
      #pragma unroll
      for (int mi = 0; mi < MPW; ++mi)
        acc[mi][nt] = __builtin_amdgcn_mfma_f32_16x16x32_bf16(afr[mi][kt], bfr, acc[mi][nt], 0, 0, 0);
    }
  }

  // ---- group stats on raw y ----
  float sg[NG], qg[NG];
  #pragma unroll
  for (int g = 0; g < NG; ++g){ sg[g] = 0.f; qg[g] = 0.f; }
  #pragma unroll
  for (int mi = 0; mi < MPW; ++mi)
    #pragma unroll
    for (int nt = 0; nt < NT; ++nt)
      #pragma unroll
      for (int rg = 0; rg < 4; ++rg){
        float y = acc[mi][nt][rg];
        sg[nt >> 1] += y;
        qg[nt >> 1] = fmaf(y, y, qg[nt >> 1]);
      }

  if constexpr (MODE_OUT == 0){
    // Y -> LDS (pad-72 rows) -> coalesced 128B/thread global store
    __syncthreads();   // all waves done reading Xl as X
    #pragma unroll
    for (int mi = 0; mi < MPW; ++mi)
      #pragma unroll
      for (int nt = 0; nt < NT; ++nt)
        #pragma unroll
        for (int rg = 0; rg < 4; ++rg)
          Xl[(w * MPW * 16 + mi * 16 + quad * 4 + rg) * YPAD + nt * 16 + col] =
              f2bf(acc[mi][nt][rg]);
    __syncthreads();
    uint4* dst = (uint4*)xout + (row0 + t) * 8;
    const uint4* srcy = (const uint4*)&Xl[(size_t)t * YPAD];
    #pragma unroll
    for (int j = 0; j < 8; ++j) dst[j] = srcy[j];
  } else {
    // 1 point per wave (MPW==2): k-reduce max/min fully in-wave
    float cmx[NT], cmn[NT];
    #pragma unroll
    for (int nt = 0; nt < NT; ++nt){
      float mx = acc[0][nt][0], mn = acc[0][nt][0];
      #pragma unroll
      for (int mi = 0; mi < MPW; ++mi)
        #pragma unroll
        for (int rg = 0; rg < 4; ++rg){
          float y = acc[mi][nt][rg];
          mx = fmaxf(mx, y); mn = fminf(mn, y);
        }
      mx = fmaxf(mx, __shfl_xor(mx, 16, 64));
      mx = fmaxf(mx, __shfl_xor(mx, 32, 64));
      mn = fminf(mn, __shfl_xor(mn, 16, 64));
      mn = fminf(mn, __shfl_xor(mn, 32, 64));
      cmx[nt] = mx; cmn[nt] = mn;
    }
    if (quad == 0){
      size_t pt = (row0 >> 5) + w;
      #pragma unroll
      for (int nt = 0; nt < NT; ++nt){
        ymax[pt * 128 + nt * 16 + col] = cmx[nt];
        ymin[pt * 128 + nt * 16 + col] = cmn[nt];
      }
    }
  }

  // ---- stats epilogue: wave shfl-reduce -> LDS -> 1 atomic set per block ----
  #pragma unroll
  for (int g = 0; g < NG; ++g){
    #pragma unroll
    for (int off = 32; off > 0; off >>= 1){
      sg[g] += __shfl_down(sg[g], off, 64);
      qg[g] += __shfl_down(qg[g], off, 64);
    }
  }
  if (lane == 0){
    #pragma unroll
    for (int g = 0; g < NG; ++g){
      spart[w][g * 2 + 0] = sg[g];
      spart[w][g * 2 + 1] = qg[g];
    }
  }
  __syncthreads();
  if (t < NG * 2){
    float v = spart[0][t] + spart[1][t] + spart[2][t] + spart[3][t];
    int g = t >> 1, sq = t & 1;
    // slot = bid & 31; each slot is its own 256B region -> parallel lines
    atomicAdd(&sums[(bid & (NSLOT - 1)) * SLOTF + (b * 4 + g) * 2 + sq], v);
  }
}

// ---------------- stats finalize: reduce slots, fold GN affine into scale/bias ----
__global__ void finalize_kernel(const float* __restrict__ sums,
                                const float* __restrict__ g, const float* __restrict__ bb,
                                float* __restrict__ sc, float* __restrict__ sb, int nch){
  int t = blockIdx.x * blockDim.x + threadIdx.x;
  if (t >= 4 * nch) return;
  int b = t / nch, c = t % nch;
  int grp = c >> 5;
  float s = 0.f, s2v = 0.f;
  #pragma unroll
  for (int sl = 0; sl < NSLOT; ++sl){
    s   += sums[sl * SLOTF + (b * 4 + grp) * 2 + 0];
    s2v += sums[sl * SLOTF + (b * 4 + grp) * 2 + 1];
  }
  const float cnt = 4194304.f;   // 32 ch * K * N
  float mean = s / cnt;
  float var = s2v / cnt - mean * mean;
  float rstd = 1.f / sqrtf(var + EPS_);
  float scale = rstd * g[c];
  sc[b*nch + c] = scale;
  sb[b*nch + c] = bb[c] - mean * scale;
}

// ---------------- final: GN2+relu on k-extremum, transpose [b][n][128]->[b][128][n] ----
__global__ __launch_bounds__(256)
void out_kernel(const float* __restrict__ ymax, const float* __restrict__ ymin,
                const float* __restrict__ sc2, const float* __restrict__ sb2,
                float* __restrict__ out){
  __shared__ float tile[64 * 129];
  const int t = threadIdx.x;
  const int b = blockIdx.y;
  const int n0 = blockIdx.x * 64;
  const float4* mx4 = (const float4*)(ymax + ((size_t)b * N_ + n0) * 128);
  const float4* mn4 = (const float4*)(ymin + ((size_t)b * N_ + n0) * 128);
  #pragma unroll
  for (int i = 0; i < 8; ++i){
    int e4 = i * 256 + t;
    int nl = e4 >> 5;
    int ch0 = (e4 & 31) * 4;
    float4 vx = mx4[e4], vn = mn4[e4];
    #pragma unroll
    for (int j = 0; j < 4; ++j){
      float slope = sc2[b*128 + ch0 + j];
      float off   = sb2[b*128 + ch0 + j];
      float y = (slope >= 0.f) ? ((const float*)&vx)[j] : ((const float*)&vn)[j];
      float v = fmaf(y, slope, off);
      tile[nl*129 + ch0 + j] = v > 0.f ? v : 0.f;
    }
  }
  __syncthreads();
  const int ch = t >> 1, h = t & 1;
  float* orow = out + ((size_t)b * 128 + ch) * N_ + n0 + h * 32;
  #pragma unroll
  for (int jj = 0; jj < 8; ++jj){
    float4 v;
    #pragma unroll
    for (int c = 0; c < 4; ++c)
      ((float*)&v)[c] = tile[(h*32 + jj*4 + c)*129 + ch];
    ((float4*)orow)[jj] = v;
  }
}

extern "C" void kernel_launch(void* const* d_in, const int* in_sizes, int n_in,
                              void* d_out, int out_size, void* d_ws, size_t ws_size,
                              hipStream_t stream) {
  const float* feature = (const float*)d_in[0];
  const float* xyz     = (const float*)d_in[1];
  const float* W0 = (const float*)d_in[2];
  const float* g0 = (const float*)d_in[3];
  const float* b0 = (const float*)d_in[4];
  const float* W1 = (const float*)d_in[5];
  const float* g1 = (const float*)d_in[6];
  const float* b1 = (const float*)d_in[7];
  const float* W2 = (const float*)d_in[8];
  const float* g2 = (const float*)d_in[9];
  const float* b2 = (const float*)d_in[10];
  float* out = (float*)d_out;

  char* ws = (char*)d_ws;
  const size_t INDS_BYTES = (size_t)B_ * N_ * K_ * sizeof(int);   // 2 MiB
  const size_t XBYTES     = (size_t)B_ * N_ * K_ * 64 * 2;        // 64 MiB each
  const size_t YBYTES     = (size_t)B_ * N_ * 128 * sizeof(float);// 8 MiB each
  const int    LSF        = NSLOT * SLOTF;                        // floats per layer's slotted sums
  int* inds           = (int*)ws;
  unsigned short* x1  = (unsigned short*)(ws + INDS_BYTES);          // [2,66) MiB
  unsigned short* x0  = (unsigned short*)(ws + INDS_BYTES + XBYTES); // [66,130) MiB
  float* ymax         = (float*)(ws + INDS_BYTES + XBYTES);          // overlays dead x0
  float* ymin         = (float*)(ws + INDS_BYTES + XBYTES + YBYTES);
  float* sums         = (float*)(ws + INDS_BYTES + 2 * XBYTES);      // [3][NSLOT][SLOTF]
  float* sc0 = sums + 3 * LSF;     // [4][64]
  float* sb0 = sc0 + 256;
  float* sc1 = sb0 + 256;
  float* sb1 = sc1 + 256;
  float* sc2 = sb1 + 256;          // [4][128]
  float* sb2 = sc2 + 512;

  hipMemsetAsync(sums, 0, 3 * LSF * sizeof(float), stream);

  ball_kernel<<<B_ * N_ / 4, 256, 0, stream>>>(xyz, inds);

  const int MROWS = B_ * N_ * K_;   // 524288

  // layer 0: gather/concat -> MFMA -> raw bf16 x0 + stats
  conv_gemm<64, 0, 0, 4><<<MROWS / 256, 256, 0, stream>>>(
      feature, xyz, inds, nullptr, nullptr, nullptr,
      W0, x0, sums + 0 * LSF, nullptr, nullptr);
  finalize_kernel<<<1, 256, 0, stream>>>(sums + 0 * LSF, g0, b0, sc0, sb0, 64);

  // layer 1: GN0+relu(x0) -> MFMA -> raw bf16 x1 + stats
  conv_gemm<64, 1, 0, 4><<<MROWS / 256, 256, 0, stream>>>(
      nullptr, nullptr, nullptr, x0, sc0, sb0,
      W1, x1, sums + 1 * LSF, nullptr, nullptr);
  finalize_kernel<<<1, 256, 0, stream>>>(sums + 1 * LSF, g1, b1, sc1, sb1, 64);

  // layer 2: GN1+relu(x1) -> MFMA -> stats + max/min over k
  conv_gemm<128, 1, 2, 2><<<MROWS / 128, 256, 0, stream>>>(
      nullptr, nullptr, nullptr, x1, sc1, sb1,
      W2, nullptr, sums + 2 * LSF, ymax, ymin);
  finalize_kernel<<<2, 256, 0, stream>>>(sums + 2 * LSF, g2, b2, sc2, sb2, 128);

  // final: GN2+relu on extremum + transpose to [b][128][n]
  dim3 ogrid(N_ / 64, B_);
  out_kernel<<<ogrid, 256, 0, stream>>>(ymax, ymin, sc2, sb2, out);
}